// Round 11
// baseline (467.180 us; speedup 1.0000x reference)
//
#include <hip/hip_runtime.h>

#define BB 2048
#define SS 200
#define VV 50257
#define EE 60
#define HH 30
#define EMBD 20
#define XD 80
#define G4 120
#define NCHUNK 50       /* 1024-col groups (k_vsum) */
#define VPAD 51200
#define RPB 8           /* rows per k_vwrite block */
#define CROW 524        /* stage row stride (dwords): 515 needed, pad to 524 (bank-friendly) */

#define O_COV ((size_t)BB*VV)
#define O_H   (O_COV + (size_t)BB*SS)
#define O_C   (O_H + (size_t)BB*HH)
#define O_NA  (O_C + (size_t)BB*HH)
#define O_LOSS (O_NA + (size_t)BB*SS)

typedef __attribute__((ext_vector_type(8))) short short8v;
typedef __attribute__((ext_vector_type(4))) float f32x4;

__device__ __forceinline__ float sigf(float x){ return 1.f/(1.f+__expf(-x)); }

__device__ __forceinline__ short f2bf(float f){
  union { __bf16 h; short s; } u; u.h = (__bf16)f; return u.s;
}

__device__ __forceinline__ float bsum(float v, float* red, int tid){
  #pragma unroll
  for (int off=32; off; off>>=1) v += __shfl_xor(v, off);
  __syncthreads();
  if ((tid&63)==0) red[tid>>6]=v;
  __syncthreads();
  return red[0]+red[1]+red[2]+red[3];
}
__device__ __forceinline__ float bmax(float v, float* red, int tid){
  #pragma unroll
  for (int off=32; off; off>>=1) v = fmaxf(v, __shfl_xor(v, off));
  __syncthreads();
  if ((tid&63)==0) red[tid>>6]=v;
  __syncthreads();
  return fmaxf(fmaxf(red[0],red[1]),fmaxf(red[2],red[3]));
}

// ---- pack v_w -> bf16 [VPAD][32] (k zero-padded), v_b -> f32 [VPAD] (-1e30 pad) ----
__global__ __launch_bounds__(256) void k_pack(
  const float* __restrict__ v_w, const float* __restrict__ v_b,
  short* __restrict__ vw_bf, float* __restrict__ vb_pad)
{
  const int idx = blockIdx.x*256 + threadIdx.x;
  const int col = idx>>2, q = idx&3;
  union { short8v v; short s[8]; } u;
  #pragma unroll
  for (int j=0;j<8;j++){
    int k = q*8+j;
    u.s[j] = (col<VV && k<HH) ? f2bf(v_w[(size_t)col*HH+k]) : (short)0;
  }
  ((short8v*)vw_bf)[idx] = u.v;
  if (q==0) vb_pad[col] = (col<VV) ? v_b[col] : -1e30f;
}

// One block per batch row: context einsum + LSTM + attention energy + softmax
// + coverage, from a single LDS-staged copy of enc_out[b]. Also emits packed h.
__global__ __launch_bounds__(256) void k_row(
  const float* __restrict__ coverage, const float* __restrict__ enc_out,
  const float* __restrict__ h0, const float* __restrict__ c0,
  const float* __restrict__ attn, const int* __restrict__ dec_input,
  const float* __restrict__ embedding,
  const float* __restrict__ w_ih, const float* __restrict__ w_hh,
  const float* __restrict__ b_ih, const float* __restrict__ b_hh,
  const float* __restrict__ attn_wh_w, const float* __restrict__ attn_wh_b,
  const float* __restrict__ attn_ws_w, const float* __restrict__ attn_ws_b,
  const float* __restrict__ attn_wc, const float* __restrict__ attn_v,
  const float* __restrict__ whv, const float* __restrict__ wsv, const float* __restrict__ wxv,
  float* __restrict__ out, float* __restrict__ pgen_ws,
  float* __restrict__ losspart_ws, short* __restrict__ h_bf)
{
  const int b = blockIdx.x, tid = threadIdx.x;
  __shared__ float enc[SS*61];
  __shared__ float wT[EE*32];
  __shared__ float attn_s[SS], cov_s[SS];
  __shared__ float xls[XD], hls[HH], wsapp[HH], wc_s[HH], v_s[HH], gls[G4];
  __shared__ float ctxp[EE*4];
  __shared__ float red[4];

  {
    const float4* ep = (const float4*)(enc_out + (size_t)b*(SS*EE));
    #pragma unroll
    for (int it=0; it<12; ++it){
      int i = tid + it*256;
      if (i < (SS*EE/4)) {
        float4 v = ep[i];
        int s = i/15, e4 = (i - s*15)*4;
        float* d = &enc[s*61+e4];
        d[0]=v.x; d[1]=v.y; d[2]=v.z; d[3]=v.w;
      }
    }
  }
  if (tid < SS) { attn_s[tid]=attn[(size_t)b*SS+tid]; cov_s[tid]=coverage[(size_t)b*SS+tid]; }
  for (int i=tid; i<EE*HH; i+=256){ int h=i/EE, e=i-h*EE; wT[e*32+h]=attn_wh_w[i]; }
  if (tid >= 256-HH) { int h = tid-(256-HH); wc_s[h]=attn_wc[h]; v_s[h]=attn_v[h]; }
  __syncthreads();

  if (tid < 240){
    int g = tid/60, e = tid - g*60;
    float acc=0.f;
    for (int s=g; s<SS; s+=4) acc += attn_s[s]*enc[s*61+e];
    ctxp[e*4+g]=acc;
  }
  __syncthreads();
  if (tid < EE) xls[tid]=ctxp[tid*4]+ctxp[tid*4+1]+ctxp[tid*4+2]+ctxp[tid*4+3];
  else if (tid < EE+EMBD){
    int k = tid-EE;
    int dix = dec_input[b];
    xls[tid] = embedding[(size_t)dix*EMBD+k];
  }
  __syncthreads();

  if (tid < G4){
    float acc = b_ih[tid]+b_hh[tid];
    const float* wi = w_ih + tid*XD;
    #pragma unroll
    for (int k=0;k<XD;k++) acc += xls[k]*wi[k];
    const float* whh = w_hh + tid*HH;
    const float* h0b = h0 + (size_t)b*HH;
    #pragma unroll
    for (int k=0;k<HH;k++) acc += h0b[k]*whh[k];
    gls[tid]=acc;
  }
  __syncthreads();
  if (tid < HH){
    float c = sigf(gls[tid+HH])*c0[(size_t)b*HH+tid] + sigf(gls[tid])*tanhf(gls[tid+2*HH]);
    float h = sigf(gls[tid+3*HH])*tanhf(c);
    out[O_C+(size_t)b*HH+tid]=c;
    out[O_H+(size_t)b*HH+tid]=h;
    hls[tid]=h;
  }
  __syncthreads();
  if (tid < 4){
    union { short8v v; short s[8]; } u;
    #pragma unroll
    for (int j=0;j<8;j++){ int k=tid*8+j; u.s[j] = (k<HH)? f2bf(hls[k]) : (short)0; }
    ((short8v*)(h_bf + (size_t)b*32))[tid] = u.v;
  }
  if (tid < HH){
    float acc = attn_ws_b[tid] + attn_wh_b[tid];
    const float* w = attn_ws_w + tid*HH;
    #pragma unroll
    for (int k=0;k<HH;k++) acc += hls[k]*w[k];
    wsapp[tid]=acc;
  }
  float pv=0.f;
  if (tid<EE) pv = xls[tid]*whv[tid];
  else if (tid<EE+HH) pv = hls[tid-EE]*wsv[tid-EE];
  else if (tid<EE+HH+EMBD) pv = xls[EE+(tid-EE-HH)]*wxv[tid-EE-HH];
  float pg = sigf(bsum(pv,red,tid));
  if (tid==0) pgen_ws[b]=pg;
  __syncthreads();

  float en = -1e30f;
  if (tid < SS){
    float acc[HH];
    float cv = cov_s[tid];
    #pragma unroll
    for (int h=0;h<HH;h++) acc[h] = wsapp[h] + cv*wc_s[h];
    for (int e=0;e<EE;e++){
      float evv = enc[tid*61+e];
      #pragma unroll
      for (int h=0;h<HH;h++) acc[h] += evv*wT[e*32+h];
    }
    float e2=0.f;
    #pragma unroll
    for (int h=0;h<HH;h++) e2 += tanhf(acc[h])*v_s[h];
    en = e2;
  }
  float mx = bmax(en, red, tid);
  float ex = (tid<SS)? __expf(en-mx) : 0.f;
  float sm = bsum(ex, red, tid);
  float inv = 1.f/sm;
  float lossv = 0.f;
  if (tid<SS){
    float na = ex*inv;
    float cv = cov_s[tid];
    out[O_NA+(size_t)b*SS+tid]=na;
    out[O_COV+(size_t)b*SS+tid]=cv+na;
    lossv = fminf(na,cv);
  }
  float ls = bsum(lossv,red,tid);
  if (tid==0) losspart_ws[b]=ls;
}

// ---- vocab pass 1 (MFMA, LDS-free): wave = 16 rows x 1024 cols ----
__global__ __launch_bounds__(256) void k_vsum(
  const short* __restrict__ vw_bf, const float* __restrict__ vb_pad,
  const short* __restrict__ h_bf, float* __restrict__ partial)
{
  const int tid = threadIdx.x;
  const int w = tid>>6, l = tid&63;
  const int lc = l&15, lg = l>>4;
  const int task = blockIdx.x*4 + w;          // 0..6399
  const int rg = task & 127, cg = task >> 7;  // 128 row-groups x 50 col-groups
  const int rbase = rg*16, cbase = cg*1024;

  short8v Af = *(const short8v*)(h_bf + (size_t)(rbase+lc)*32 + lg*8);

  float psum[4] = {0.f,0.f,0.f,0.f};
  #pragma unroll 4
  for (int t=0;t<64;t++){
    const int col = cbase + t*16 + lc;
    short8v Bf = *(const short8v*)(vw_bf + (size_t)col*32 + lg*8);
    const float vb = vb_pad[col];
    f32x4 z = {0.f,0.f,0.f,0.f};
    f32x4 d = __builtin_amdgcn_mfma_f32_16x16x32_bf16(Af, Bf, z, 0,0,0);
    psum[0] += __expf(d[0]+vb);
    psum[1] += __expf(d[1]+vb);
    psum[2] += __expf(d[2]+vb);
    psum[3] += __expf(d[3]+vb);
  }
  #pragma unroll
  for (int r=0;r<4;r++){
    float s = psum[r];
    s += __shfl_xor(s,1); s += __shfl_xor(s,2); s += __shfl_xor(s,4); s += __shfl_xor(s,8);
    if (lc==0) partial[(size_t)cg*BB + rbase + lg*4 + r] = s;
  }
}

// ---- offs[row] = log(pgen[row]) - log(sum_c partial[c][row]) ----
__global__ __launch_bounds__(256) void k_off(
  const float* __restrict__ partial, const float* __restrict__ pgen,
  float* __restrict__ offs)
{
  const int row = blockIdx.x*256 + threadIdx.x;
  float s=0.f;
  #pragma unroll 5
  for (int c=0;c<NCHUNK;c++) s += partial[(size_t)c*BB + row];
  offs[row] = __logf(pgen[row]) - __logf(s);
}

// ---- vocab pass 2 (MFMA) + fused pointer scatter, 1KB-per-instruction flush ----
// Block = 8 rows x 12800 cols (grid 256 x 4). Per 512-col chunk: MFMA+exp into
// LDS stage (per-row pre-shifted by a = (row*VV+c0)&3), LDS RMW for last-wins
// scatter entries, then flush: per row, p head scalars + 127 aligned f32x4
// stores (64-lane instruction = 1KB contiguous aligned, like the 6.8TB/s fill)
// + (4-p) tail scalars. Uniform per chunk; no gaps, no cross-chunk values.
__global__ __launch_bounds__(256) void k_vwrite(
  const short* __restrict__ vw_bf, const float* __restrict__ vb_pad,
  const short* __restrict__ h_bf, const float* __restrict__ offs,
  const float* __restrict__ pgen, const int* __restrict__ enc_inputs,
  const float* __restrict__ na_src, float* __restrict__ out)
{
  __shared__ short h_lds[16*32];
  __shared__ float stage[RPB*CROW];
  const int tid = threadIdx.x;
  const int rbase = blockIdx.x*RPB;
  const int cstart = blockIdx.y*12800;

  // A-fragment rows: 8 real rows + 8 zero rows
  if (tid < 64){
    const int row = tid>>2;
    uint4 z4 = {0,0,0,0};
    ((uint4*)h_lds)[tid] = (row < RPB)
      ? ((const uint4*)(h_bf + (size_t)(rbase+row)*32))[tid&3] : z4;
  }

  // ---- scatter prep in aliased LDS (RPB*SS ints = 6.4KB < stage) ----
  int* sidx = (int*)stage;
  for (int e=tid; e<RPB*SS; e+=256){
    int i = e/SS, s = e - i*SS;
    sidx[e] = enc_inputs[(size_t)(rbase+i)*SS + s];
  }
  __syncthreads();
  int   ridx[7]; float rval[7]; int rrow[7]; int rsh[7];
  #pragma unroll
  for (int k=0;k<7;k++){
    const int e = tid + k*256;
    ridx[k] = -1; rrow[k] = 0; rval[k] = 0.f; rsh[k] = 0;
    if (e < RPB*SS){
      const int i = e/SS, s = e - i*SS;
      const int idx = sidx[e];
      bool last = true;
      for (int s2=s+1; s2<SS; s2++) if (sidx[i*SS+s2]==idx){ last=false; break; }
      if (last){
        ridx[k] = idx; rrow[k] = i;
        rval[k] = (1.f - pgen[rbase+i]) * na_src[(size_t)(rbase+i)*SS + s];
        rsh[k]  = (int)(((size_t)(rbase+i)*VV + (size_t)cstart) & 3);
      }
    }
  }
  __syncthreads();   // sidx dead; stage reusable

  const int w = tid>>6, l = tid&63;
  const int lc = l&15, lg = l>>4;

  short8v Af = *(const short8v*)&h_lds[lc*32 + lg*8];
  float offv[4] = {0.f,0.f,0.f,0.f};
  int   av[4]   = {0,0,0,0};
  if (lg < 2){
    #pragma unroll
    for (int r=0;r<4;r++){
      const int row = rbase + lg*4 + r;
      offv[r] = offs[row];
      av[r]   = (int)(((size_t)row*VV + (size_t)cstart) & 3);
    }
  }

  for (int c=0;c<25;c++){
    const int c0 = cstart + c*512;
    if (c0 >= VV) break;   // uniform across block (y=3 tail)
    // ---- compute & stage: wave w covers cols [c0+w*128, +128) ----
    #pragma unroll
    for (int t=0;t<8;t++){
      const int cl = w*128 + t*16 + lc;
      const int col = c0 + cl;
      short8v Bf = *(const short8v*)(vw_bf + (size_t)col*32 + lg*8);
      const float vb = vb_pad[col];
      f32x4 z = {0.f,0.f,0.f,0.f};
      f32x4 d = __builtin_amdgcn_mfma_f32_16x16x32_bf16(Af, Bf, z, 0,0,0);
      if (lg < 2){
        #pragma unroll
        for (int r=0;r<4;r++)
          stage[(lg*4+r)*CROW + av[r] + cl] = __expf(d[r]+vb+offv[r]);
      }
    }
    __syncthreads();
    // ---- fused scatter: unique (row,idx) -> race-free LDS RMW ----
    #pragma unroll
    for (int k=0;k<7;k++){
      if ((unsigned)(ridx[k]-c0) < 512u)
        stage[rrow[k]*CROW + rsh[k] + (ridx[k]-c0)] += rval[k];
    }
    __syncthreads();
    // ---- flush ----
    if (c0 + 512 <= VV){
      // wave w flushes rows 2w, 2w+1
      #pragma unroll
      for (int rr=0;rr<2;rr++){
        const int row_l = w*2 + rr;
        const size_t G = (size_t)(rbase+row_l)*VV + (size_t)c0;
        const int a = (int)(G & 3), p = (4-a)&3;
        const float* sp = &stage[row_l*CROW];
        const int base = a + p;                  // 0 or 4
        // 127 aligned f32x4: m=l and m=64+l
        f32x4 v0 = *(const f32x4*)(sp + base + 4*l);
        *(f32x4*)(out + G + p + 4*l) = v0;
        if (l < 63){
          f32x4 v1 = *(const f32x4*)(sp + base + 256 + 4*l);
          *(f32x4*)(out + G + p + 256 + 4*l) = v1;
        }
        // patch scalars: head p, tail 4-p
        if (l < p) out[G + l] = sp[a + l];
        else if (l >= 8 && l < 8 + (4-p)){
          const int j = 508 + p + (l-8);
          out[G + j] = sp[a + j];
        }
      }
    } else {
      // boundary chunk (y=3 only): guarded scalar flush
      for (int i=0;i<RPB;i++){
        const size_t Gr = (size_t)(rbase+i)*VV;
        const int a = (int)((Gr + (size_t)c0) & 3);
        #pragma unroll
        for (int j=0;j<2;j++){
          const int col = c0 + j*256 + tid;
          if (col < VV) out[Gr + col] = stage[i*CROW + a + (col - c0)];
        }
      }
    }
    __syncthreads();
  }
}

__global__ __launch_bounds__(256) void k_loss(const float* __restrict__ lp, float* __restrict__ dst){
  __shared__ float red[4];
  int tid=threadIdx.x;
  float s=0.f;
  for (int i=tid;i<BB;i+=256) s+=lp[i];
  #pragma unroll
  for (int off=32; off; off>>=1) s+=__shfl_xor(s,off);
  if ((tid&63)==0) red[tid>>6]=s;
  __syncthreads();
  if (tid==0) dst[0]=red[0]+red[1]+red[2]+red[3];
}

extern "C" void kernel_launch(void* const* d_in, const int* in_sizes, int n_in,
                              void* d_out, int out_size, void* d_ws, size_t ws_size,
                              hipStream_t stream)
{
  const float* coverage =(const float*)d_in[0];
  const float* enc_out  =(const float*)d_in[1];
  const float* h0       =(const float*)d_in[2];
  const float* c0       =(const float*)d_in[3];
  const float* attn     =(const float*)d_in[4];
  const int*   dec_input=(const int*)d_in[5];
  const int*   enc_inputs=(const int*)d_in[6];
  const float* embedding=(const float*)d_in[7];
  const float* w_ih     =(const float*)d_in[8];
  const float* w_hh     =(const float*)d_in[9];
  const float* b_ih     =(const float*)d_in[10];
  const float* b_hh     =(const float*)d_in[11];
  const float* attn_wh_w=(const float*)d_in[12];
  const float* attn_wh_b=(const float*)d_in[13];
  const float* attn_ws_w=(const float*)d_in[14];
  const float* attn_ws_b=(const float*)d_in[15];
  const float* attn_wc  =(const float*)d_in[16];
  const float* attn_v   =(const float*)d_in[17];
  const float* whv      =(const float*)d_in[18];
  const float* wsv      =(const float*)d_in[19];
  const float* wxv      =(const float*)d_in[20];
  const float* v_w      =(const float*)d_in[21];
  const float* v_b      =(const float*)d_in[22];
  float* out=(float*)d_out;
  float* wsf=(float*)d_ws;
  float* pgen    = wsf;
  float* losspart= wsf + 2048;
  float* offs    = wsf + 4096;
  float* partial = wsf + 6144;
  float* vb_pad  = wsf + 6144 + (size_t)NCHUNK*BB;
  short* vw_bf   = (short*)(vb_pad + VPAD);
  short* h_bf    = vw_bf + (size_t)VPAD*32;

  k_pack<<<VPAD*4/256,256,0,stream>>>(v_w,v_b,vw_bf,vb_pad);

  k_row<<<BB,256,0,stream>>>(coverage,enc_out,h0,c0,attn,dec_input,embedding,
    w_ih,w_hh,b_ih,b_hh,attn_wh_w,attn_wh_b,attn_ws_w,attn_ws_b,attn_wc,attn_v,
    whv,wsv,wxv,out,pgen,losspart,h_bf);

  k_vsum  <<<1600,256,0,stream>>>(vw_bf,vb_pad,h_bf,partial);
  k_off   <<<BB/256,256,0,stream>>>(partial,pgen,offs);
  dim3 gw(BB/RPB, 4);   // 256 row-groups x 4 column-quarters
  k_vwrite<<<gw,256,0,stream>>>(vw_bf,vb_pad,h_bf,offs,pgen,enc_inputs,out+O_NA,out);
  k_loss<<<1,256,0,stream>>>(losspart,out+O_LOSS);
}

// Round 12
// 343.614 us; speedup vs baseline: 1.3596x; 1.3596x over previous
//
#include <hip/hip_runtime.h>

#define BB 2048
#define SS 200
#define VV 50257
#define EE 60
#define HH 30
#define EMBD 20
#define XD 80
#define G4 120
#define NCHUNK 50       /* 1024-col groups (k_vsum) */
#define VPAD 51200

#define O_COV ((size_t)BB*VV)
#define O_H   (O_COV + (size_t)BB*SS)
#define O_C   (O_H + (size_t)BB*HH)
#define O_NA  (O_C + (size_t)BB*HH)
#define O_LOSS (O_NA + (size_t)BB*SS)

typedef __attribute__((ext_vector_type(8))) short short8v;
typedef __attribute__((ext_vector_type(4))) float f32x4;
typedef __attribute__((ext_vector_type(4), aligned(4))) float f32x4u;  /* 4B-aligned vector store */

__device__ __forceinline__ float sigf(float x){ return 1.f/(1.f+__expf(-x)); }

__device__ __forceinline__ short f2bf(float f){
  union { __bf16 h; short s; } u; u.h = (__bf16)f; return u.s;
}

__device__ __forceinline__ float bsum(float v, float* red, int tid){
  #pragma unroll
  for (int off=32; off; off>>=1) v += __shfl_xor(v, off);
  __syncthreads();
  if ((tid&63)==0) red[tid>>6]=v;
  __syncthreads();
  return red[0]+red[1]+red[2]+red[3];
}
__device__ __forceinline__ float bmax(float v, float* red, int tid){
  #pragma unroll
  for (int off=32; off; off>>=1) v = fmaxf(v, __shfl_xor(v, off));
  __syncthreads();
  if ((tid&63)==0) red[tid>>6]=v;
  __syncthreads();
  return fmaxf(fmaxf(red[0],red[1]),fmaxf(red[2],red[3]));
}

// ---- pack v_w -> bf16 [VPAD][32] (k zero-padded), v_b -> f32 [VPAD] (-1e30 pad) ----
__global__ __launch_bounds__(256) void k_pack(
  const float* __restrict__ v_w, const float* __restrict__ v_b,
  short* __restrict__ vw_bf, float* __restrict__ vb_pad)
{
  const int idx = blockIdx.x*256 + threadIdx.x;
  const int col = idx>>2, q = idx&3;
  union { short8v v; short s[8]; } u;
  #pragma unroll
  for (int j=0;j<8;j++){
    int k = q*8+j;
    u.s[j] = (col<VV && k<HH) ? f2bf(v_w[(size_t)col*HH+k]) : (short)0;
  }
  ((short8v*)vw_bf)[idx] = u.v;
  if (q==0) vb_pad[col] = (col<VV) ? v_b[col] : -1e30f;
}

// One block per batch row: context einsum + LSTM + attention energy + softmax
// + coverage, from a single LDS-staged copy of enc_out[b]. Also emits packed h.
__global__ __launch_bounds__(256) void k_row(
  const float* __restrict__ coverage, const float* __restrict__ enc_out,
  const float* __restrict__ h0, const float* __restrict__ c0,
  const float* __restrict__ attn, const int* __restrict__ dec_input,
  const float* __restrict__ embedding,
  const float* __restrict__ w_ih, const float* __restrict__ w_hh,
  const float* __restrict__ b_ih, const float* __restrict__ b_hh,
  const float* __restrict__ attn_wh_w, const float* __restrict__ attn_wh_b,
  const float* __restrict__ attn_ws_w, const float* __restrict__ attn_ws_b,
  const float* __restrict__ attn_wc, const float* __restrict__ attn_v,
  const float* __restrict__ whv, const float* __restrict__ wsv, const float* __restrict__ wxv,
  float* __restrict__ out, float* __restrict__ pgen_ws,
  float* __restrict__ losspart_ws, short* __restrict__ h_bf)
{
  const int b = blockIdx.x, tid = threadIdx.x;
  __shared__ float enc[SS*61];
  __shared__ float wT[EE*32];
  __shared__ float attn_s[SS], cov_s[SS];
  __shared__ float xls[XD], hls[HH], wsapp[HH], wc_s[HH], v_s[HH], gls[G4];
  __shared__ float ctxp[EE*4];
  __shared__ float red[4];

  {
    const float4* ep = (const float4*)(enc_out + (size_t)b*(SS*EE));
    #pragma unroll
    for (int it=0; it<12; ++it){
      int i = tid + it*256;
      if (i < (SS*EE/4)) {
        float4 v = ep[i];
        int s = i/15, e4 = (i - s*15)*4;
        float* d = &enc[s*61+e4];
        d[0]=v.x; d[1]=v.y; d[2]=v.z; d[3]=v.w;
      }
    }
  }
  if (tid < SS) { attn_s[tid]=attn[(size_t)b*SS+tid]; cov_s[tid]=coverage[(size_t)b*SS+tid]; }
  for (int i=tid; i<EE*HH; i+=256){ int h=i/EE, e=i-h*EE; wT[e*32+h]=attn_wh_w[i]; }
  if (tid >= 256-HH) { int h = tid-(256-HH); wc_s[h]=attn_wc[h]; v_s[h]=attn_v[h]; }
  __syncthreads();

  if (tid < 240){
    int g = tid/60, e = tid - g*60;
    float acc=0.f;
    for (int s=g; s<SS; s+=4) acc += attn_s[s]*enc[s*61+e];
    ctxp[e*4+g]=acc;
  }
  __syncthreads();
  if (tid < EE) xls[tid]=ctxp[tid*4]+ctxp[tid*4+1]+ctxp[tid*4+2]+ctxp[tid*4+3];
  else if (tid < EE+EMBD){
    int k = tid-EE;
    int dix = dec_input[b];
    xls[tid] = embedding[(size_t)dix*EMBD+k];
  }
  __syncthreads();

  if (tid < G4){
    float acc = b_ih[tid]+b_hh[tid];
    const float* wi = w_ih + tid*XD;
    #pragma unroll
    for (int k=0;k<XD;k++) acc += xls[k]*wi[k];
    const float* whh = w_hh + tid*HH;
    const float* h0b = h0 + (size_t)b*HH;
    #pragma unroll
    for (int k=0;k<HH;k++) acc += h0b[k]*whh[k];
    gls[tid]=acc;
  }
  __syncthreads();
  if (tid < HH){
    float c = sigf(gls[tid+HH])*c0[(size_t)b*HH+tid] + sigf(gls[tid])*tanhf(gls[tid+2*HH]);
    float h = sigf(gls[tid+3*HH])*tanhf(c);
    out[O_C+(size_t)b*HH+tid]=c;
    out[O_H+(size_t)b*HH+tid]=h;
    hls[tid]=h;
  }
  __syncthreads();
  if (tid < 4){
    union { short8v v; short s[8]; } u;
    #pragma unroll
    for (int j=0;j<8;j++){ int k=tid*8+j; u.s[j] = (k<HH)? f2bf(hls[k]) : (short)0; }
    ((short8v*)(h_bf + (size_t)b*32))[tid] = u.v;
  }
  if (tid < HH){
    float acc = attn_ws_b[tid] + attn_wh_b[tid];
    const float* w = attn_ws_w + tid*HH;
    #pragma unroll
    for (int k=0;k<HH;k++) acc += hls[k]*w[k];
    wsapp[tid]=acc;
  }
  float pv=0.f;
  if (tid<EE) pv = xls[tid]*whv[tid];
  else if (tid<EE+HH) pv = hls[tid-EE]*wsv[tid-EE];
  else if (tid<EE+HH+EMBD) pv = xls[EE+(tid-EE-HH)]*wxv[tid-EE-HH];
  float pg = sigf(bsum(pv,red,tid));
  if (tid==0) pgen_ws[b]=pg;
  __syncthreads();

  float en = -1e30f;
  if (tid < SS){
    float acc[HH];
    float cv = cov_s[tid];
    #pragma unroll
    for (int h=0;h<HH;h++) acc[h] = wsapp[h] + cv*wc_s[h];
    for (int e=0;e<EE;e++){
      float evv = enc[tid*61+e];
      #pragma unroll
      for (int h=0;h<HH;h++) acc[h] += evv*wT[e*32+h];
    }
    float e2=0.f;
    #pragma unroll
    for (int h=0;h<HH;h++) e2 += tanhf(acc[h])*v_s[h];
    en = e2;
  }
  float mx = bmax(en, red, tid);
  float ex = (tid<SS)? __expf(en-mx) : 0.f;
  float sm = bsum(ex, red, tid);
  float inv = 1.f/sm;
  float lossv = 0.f;
  if (tid<SS){
    float na = ex*inv;
    float cv = cov_s[tid];
    out[O_NA+(size_t)b*SS+tid]=na;
    out[O_COV+(size_t)b*SS+tid]=cv+na;
    lossv = fminf(na,cv);
  }
  float ls = bsum(lossv,red,tid);
  if (tid==0) losspart_ws[b]=ls;
}

// ---- vocab pass 1 (swapped MFMA, LDS-free): wave = 16 rows x 1024 cols ----
// A = v_w tile (vocab as M), B = h tile (rows as N): D[m=4*lg+r][n=lc].
// Lane-local partial per row; two shfl_xor folds; lanes 0..15 write.
__global__ __launch_bounds__(256) void k_vsum(
  const short* __restrict__ vw_bf, const float* __restrict__ vb_pad,
  const short* __restrict__ h_bf, float* __restrict__ partial)
{
  const int tid = threadIdx.x;
  const int w = tid>>6, l = tid&63;
  const int lc = l&15, lg = l>>4;
  const int task = blockIdx.x*4 + w;          // 0..6399
  const int rg = task & 127, cg = task >> 7;  // 128 row-groups x 50 col-groups
  const int rbase = rg*16, cbase = cg*1024;

  short8v Bh = *(const short8v*)(h_bf + (size_t)(rbase+lc)*32 + lg*8);

  float ps = 0.f;
  #pragma unroll 4
  for (int t=0;t<64;t++){
    const int ct = cbase + t*16;
    short8v Av = *(const short8v*)(vw_bf + (size_t)(ct+lc)*32 + lg*8);
    f32x4 vb4 = *(const f32x4*)(vb_pad + ct + lg*4);
    f32x4 z = {0.f,0.f,0.f,0.f};
    f32x4 d = __builtin_amdgcn_mfma_f32_16x16x32_bf16(Av, Bh, z, 0,0,0);
    ps += __expf(d[0]+vb4[0]) + __expf(d[1]+vb4[1])
        + __expf(d[2]+vb4[2]) + __expf(d[3]+vb4[3]);
  }
  ps += __shfl_xor(ps,16);
  ps += __shfl_xor(ps,32);
  if (l < 16) partial[(size_t)cg*BB + rbase + lc] = ps;
}

// ---- offs[row] = log(pgen[row]) - log(sum_c partial[c][row]) ----
__global__ __launch_bounds__(256) void k_off(
  const float* __restrict__ partial, const float* __restrict__ pgen,
  float* __restrict__ offs)
{
  const int row = blockIdx.x*256 + threadIdx.x;
  float s=0.f;
  #pragma unroll 5
  for (int c=0;c<NCHUNK;c++) s += partial[(size_t)c*BB + row];
  offs[row] = __logf(pgen[row]) - __logf(s);
}

// ---- vocab pass 2 (swapped MFMA, register-direct stores) ----
// Wave = 16 rows x 1600 cols (100 tiles). Per tile: 1 A-load (1KB contiguous,
// L2-hot) + 1 MFMA + 4 exp + ONE float4 store per lane (4 consecutive vocab
// probs of one row, straight from the accumulator). No LDS, no barriers ->
// stores pipeline as deep as the memset fill.
__global__ __launch_bounds__(256) void k_vwrite(
  const short* __restrict__ vw_bf, const float* __restrict__ vb_pad,
  const short* __restrict__ h_bf, const float* __restrict__ offs,
  float* __restrict__ out)
{
  const int tid = threadIdx.x;
  const int w = tid>>6, l = tid&63;
  const int lc = l&15, lg = l>>4;
  const int task = blockIdx.x*4 + w;          // 0..4095
  const int rg = task & 127, cg = task >> 7;  // 128 row-groups x 32 col-groups
  const int rbase = rg*16, cbase = cg*1600;

  short8v Bh = *(const short8v*)(h_bf + (size_t)(rbase+lc)*32 + lg*8);
  const int row = rbase + lc;
  const float off = offs[row];
  float* orow = out + (size_t)row*VV;

  #pragma unroll 2
  for (int t=0;t<100;t++){
    const int ct = cbase + t*16;
    const int v0 = ct + lg*4;
    short8v Av = *(const short8v*)(vw_bf + (size_t)(ct+lc)*32 + lg*8);
    f32x4 vb4 = *(const f32x4*)(vb_pad + v0);
    f32x4 z = {0.f,0.f,0.f,0.f};
    f32x4 d = __builtin_amdgcn_mfma_f32_16x16x32_bf16(Av, Bh, z, 0,0,0);
    f32x4 o;
    o[0] = __expf(d[0]+vb4[0]+off);
    o[1] = __expf(d[1]+vb4[1]+off);
    o[2] = __expf(d[2]+vb4[2]+off);
    o[3] = __expf(d[3]+vb4[3]+off);
    if (v0 + 4 <= VV){
      *(f32x4u*)(orow + v0) = o;
    } else {
      #pragma unroll
      for (int r=0;r<4;r++) if (v0 + r < VV) orow[v0+r] = o[r];
    }
  }
}

// ---- scatter: numpy last-wins .at[rows, enc_inputs].set(new_attn), fused as += ----
__global__ __launch_bounds__(256) void k_scatter(
  const int* __restrict__ enc_inputs, const float* __restrict__ pgen,
  const float* __restrict__ na, float* __restrict__ out)
{
  __shared__ int idx_s[SS];
  const int b=blockIdx.x, tid=threadIdx.x;
  if (tid<SS) idx_s[tid]=enc_inputs[(size_t)b*SS+tid];
  __syncthreads();
  if (tid<SS){
    int idx=idx_s[tid];
    bool last=true;
    for (int s2=tid+1;s2<SS;s2++) if (idx_s[s2]==idx){ last=false; break; }
    if (last){
      float add=(1.f-pgen[b])*na[(size_t)b*SS+tid];
      out[(size_t)b*VV+idx]+=add;
    }
  }
}

__global__ __launch_bounds__(256) void k_loss(const float* __restrict__ lp, float* __restrict__ dst){
  __shared__ float red[4];
  int tid=threadIdx.x;
  float s=0.f;
  for (int i=tid;i<BB;i+=256) s+=lp[i];
  #pragma unroll
  for (int off=32; off; off>>=1) s+=__shfl_xor(s,off);
  if ((tid&63)==0) red[tid>>6]=s;
  __syncthreads();
  if (tid==0) dst[0]=red[0]+red[1]+red[2]+red[3];
}

extern "C" void kernel_launch(void* const* d_in, const int* in_sizes, int n_in,
                              void* d_out, int out_size, void* d_ws, size_t ws_size,
                              hipStream_t stream)
{
  const float* coverage =(const float*)d_in[0];
  const float* enc_out  =(const float*)d_in[1];
  const float* h0       =(const float*)d_in[2];
  const float* c0       =(const float*)d_in[3];
  const float* attn     =(const float*)d_in[4];
  const int*   dec_input=(const int*)d_in[5];
  const int*   enc_inputs=(const int*)d_in[6];
  const float* embedding=(const float*)d_in[7];
  const float* w_ih     =(const float*)d_in[8];
  const float* w_hh     =(const float*)d_in[9];
  const float* b_ih     =(const float*)d_in[10];
  const float* b_hh     =(const float*)d_in[11];
  const float* attn_wh_w=(const float*)d_in[12];
  const float* attn_wh_b=(const float*)d_in[13];
  const float* attn_ws_w=(const float*)d_in[14];
  const float* attn_ws_b=(const float*)d_in[15];
  const float* attn_wc  =(const float*)d_in[16];
  const float* attn_v   =(const float*)d_in[17];
  const float* whv      =(const float*)d_in[18];
  const float* wsv      =(const float*)d_in[19];
  const float* wxv      =(const float*)d_in[20];
  const float* v_w      =(const float*)d_in[21];
  const float* v_b      =(const float*)d_in[22];
  float* out=(float*)d_out;
  float* wsf=(float*)d_ws;
  float* pgen    = wsf;
  float* losspart= wsf + 2048;
  float* offs    = wsf + 4096;
  float* partial = wsf + 6144;
  float* vb_pad  = wsf + 6144 + (size_t)NCHUNK*BB;
  short* vw_bf   = (short*)(vb_pad + VPAD);
  short* h_bf    = vw_bf + (size_t)VPAD*32;

  k_pack<<<VPAD*4/256,256,0,stream>>>(v_w,v_b,vw_bf,vb_pad);

  k_row<<<BB,256,0,stream>>>(coverage,enc_out,h0,c0,attn,dec_input,embedding,
    w_ih,w_hh,b_ih,b_hh,attn_wh_w,attn_wh_b,attn_ws_w,attn_ws_b,attn_wc,attn_v,
    whv,wsv,wxv,out,pgen,losspart,h_bf);

  k_vsum  <<<1600,256,0,stream>>>(vw_bf,vb_pad,h_bf,partial);
  k_off   <<<BB/256,256,0,stream>>>(partial,pgen,offs);
  k_vwrite<<<1024,256,0,stream>>>(vw_bf,vb_pad,h_bf,offs,out);
  k_scatter<<<BB,256,0,stream>>>(enc_inputs,pgen,out+O_NA,out);
  k_loss<<<1,256,0,stream>>>(losspart,out+O_LOSS);
}